// Round 1
// baseline (426.265 us; speedup 1.0000x reference)
//
#include <hip/hip_runtime.h>

// Problem constants (B,T,D,H,KVH fixed by the reference)
#define NB 2
#define NT 2048
#define ND 2048
#define NH 16
#define NKVH 4
#define NHD 128
#define NHALF 64
#define NREP (NH / NKVH)
#define MFIX 12.0f  // fixed softmax max: |score| <= sqrt(128) ~= 11.32 after zc-rmsnorm

typedef __bf16 bf16x8 __attribute__((ext_vector_type(8)));
typedef unsigned short u16x8 __attribute__((ext_vector_type(8)));
typedef float f32x4 __attribute__((ext_vector_type(4)));

__device__ __forceinline__ unsigned short f2b(float f) {
  union { float f; unsigned int u; } v; v.f = f;
  unsigned int r = v.u + 0x7FFFu + ((v.u >> 16) & 1u);
  return (unsigned short)(r >> 16);
}
__device__ __forceinline__ float b2f(unsigned short h) {
  union { unsigned int u; float f; } v; v.u = ((unsigned int)h) << 16;
  return v.f;
}

// async global->LDS DMA, 16B per lane. LDS dest = wave-uniform base + lane*16.
__device__ __forceinline__ void glds16(const unsigned short* g, unsigned short* l) {
  __builtin_amdgcn_global_load_lds(
      (__attribute__((address_space(1))) unsigned int*)(unsigned long long)g,
      (__attribute__((address_space(3))) unsigned int*)(unsigned int)(unsigned long long)l,
      16, 0, 0);
}

// ---------- f32 -> bf16 elementwise (8/thread) ----------
__global__ __launch_bounds__(256) void f2bf(const float* __restrict__ in,
                                            unsigned short* __restrict__ out) {
  const size_t i = (size_t)(blockIdx.x * 256 + threadIdx.x) * 8;
  float4 a = *(const float4*)(in + i);
  float4 b = *(const float4*)(in + i + 4);
  u16x8 r;
  r[0] = f2b(a.x); r[1] = f2b(a.y); r[2] = f2b(a.z); r[3] = f2b(a.w);
  r[4] = f2b(b.x); r[5] = f2b(b.y); r[6] = f2b(b.z); r[7] = f2b(b.w);
  *(u16x8*)(out + i) = r;
}

// ---------- weight transpose + convert: in (K,N) f32 -> out (N,K) bf16 ----------
__global__ __launch_bounds__(256) void wtrans(const float* __restrict__ in,
                                              unsigned short* __restrict__ out,
                                              int K, int N) {
  __shared__ float tile[32][33];
  const int k0 = blockIdx.y * 32, n0 = blockIdx.x * 32;
  const int x = threadIdx.x & 31, y8 = threadIdx.x >> 5;
#pragma unroll
  for (int j = 0; j < 4; ++j) {
    const int y = y8 + j * 8;
    tile[y][x] = in[(size_t)(k0 + y) * N + n0 + x];
  }
  __syncthreads();
#pragma unroll
  for (int j = 0; j < 4; ++j) {
    const int y = y8 + j * 8;
    out[(size_t)(n0 + y) * K + k0 + x] = f2b(tile[x][y]);
  }
}

// ---------- MFMA GEMM: C(M,N) f32 = A(M,K)bf16 @ Bt(N,K)bf16^T ----------
// m97 structure: 128x128 tile, BK=32, linear LDS [128][32] (global_load_lds
// requires contiguous dest), 4x global_load_lds_dwordx4 per K-step, 2 barriers.
// 4 waves (2x2 of 64x64), each 4x4 mfma_f32_16x16x32_bf16.
__global__ __launch_bounds__(256) void gemm128(const unsigned short* __restrict__ A,
                                               const unsigned short* __restrict__ Bt,
                                               float* __restrict__ C,
                                               int M, int N, int K) {
  __shared__ unsigned short As[128 * 32];
  __shared__ unsigned short Bs[128 * 32];
  const int tid = threadIdx.x;
  const int wave = tid >> 6, lane = tid & 63;
  const int wm = wave >> 1, wn = wave & 1;
  const int quad = lane >> 4, c = lane & 15;
  const int m0 = blockIdx.y * 128, n0 = blockIdx.x * 128;
  const int gr = lane >> 2;        // row within this wave's 16-row chunk
  const int gc = (lane & 3) * 8;   // col in shorts (16B granules)

  // per-lane global sources; wave-uniform LDS dests (base + lane*16 is implicit)
  const unsigned short* pa0 = A + (size_t)(m0 + wave * 16 + gr) * K + gc;
  const unsigned short* pa1 = A + (size_t)(m0 + 64 + wave * 16 + gr) * K + gc;
  const unsigned short* pb0 = Bt + (size_t)(n0 + wave * 16 + gr) * K + gc;
  const unsigned short* pb1 = Bt + (size_t)(n0 + 64 + wave * 16 + gr) * K + gc;
  unsigned short* la0 = &As[(wave * 16) * 32];
  unsigned short* la1 = &As[(64 + wave * 16) * 32];
  unsigned short* lb0 = &Bs[(wave * 16) * 32];
  unsigned short* lb1 = &Bs[(64 + wave * 16) * 32];

  f32x4 acc[4][4] = {};

  for (int k0 = 0; k0 < K; k0 += 32) {
    glds16(pa0 + k0, la0);
    glds16(pa1 + k0, la1);
    glds16(pb0 + k0, lb0);
    glds16(pb1 + k0, lb1);
    __syncthreads();  // compiler emits vmcnt(0) drain here -> LDS writes landed
    bf16x8 af[4];
#pragma unroll
    for (int sm = 0; sm < 4; ++sm)
      af[sm] = *(const bf16x8*)&As[(wm * 64 + sm * 16 + c) * 32 + quad * 8];
#pragma unroll
    for (int sn = 0; sn < 4; ++sn) {
      bf16x8 bfr = *(const bf16x8*)&Bs[(wn * 64 + sn * 16 + c) * 32 + quad * 8];
#pragma unroll
      for (int sm = 0; sm < 4; ++sm)
        acc[sm][sn] = __builtin_amdgcn_mfma_f32_16x16x32_bf16(af[sm], bfr, acc[sm][sn], 0, 0, 0);
    }
    __syncthreads();
  }

#pragma unroll
  for (int sm = 0; sm < 4; ++sm)
#pragma unroll
    for (int sn = 0; sn < 4; ++sn) {
      const int row = m0 + wm * 64 + sm * 16 + quad * 4;
      const int col = n0 + wn * 64 + sn * 16 + c;
#pragma unroll
      for (int r = 0; r < 4; ++r)
        C[(size_t)(row + r) * N + col] = acc[sm][sn][r];
    }
}

// ---------- fused zc-RMSNorm + RoPE; rows (b,t,h) -> (B,nh,T,HD) bf16 ----------
__global__ __launch_bounds__(256) void rmsnorm_rope(const float* __restrict__ in,
                                                    unsigned short* __restrict__ out,
                                                    const float* __restrict__ scale,
                                                    const float* __restrict__ cosp,
                                                    const float* __restrict__ sinp,
                                                    int nh, int instride, float outscale) {
  const int wid = blockIdx.x * 4 + (threadIdx.x >> 6);
  const int lane = threadIdx.x & 63;
  const int h = wid % nh;
  const int t = (wid / nh) % NT;
  const int b = wid / (nh * NT);
  const float* x = in + (size_t)(b * NT + t) * instride + h * NHD;
  float x1 = x[lane], x2 = x[lane + NHALF];
  float ss = x1 * x1 + x2 * x2;
#pragma unroll
  for (int m = 1; m < 64; m <<= 1) ss += __shfl_xor(ss, m, 64);
  const float inv = 1.0f / sqrtf(ss * (1.0f / NHD) + 1e-6f);
  const float n1 = (1.0f + scale[lane]) * x1 * inv;
  const float n2 = (1.0f + scale[lane + NHALF]) * x2 * inv;
  const float cc = cosp[t * NHALF + lane], s = sinp[t * NHALF + lane];
  const size_t ob = (((size_t)b * nh + h) * NT + t) * NHD;
  out[ob + lane] = f2b((n1 * cc - n2 * s) * outscale);
  out[ob + lane + NHALF] = f2b((n2 * cc + n1 * s) * outscale);
}

// ---------- V transpose: rows (b,t) f32 -> (B,KVH,HD,T) bf16 ----------
__global__ __launch_bounds__(256) void vtrans(const float* __restrict__ in,
                                              unsigned short* __restrict__ out,
                                              int instride) {
  __shared__ float tile[32][33];
  const int bg = blockIdx.z;  // b*NKVH + g
  const int b = bg >> 2, g = bg & 3;
  const int t0 = blockIdx.x * 32, d0 = blockIdx.y * 32;
  const int x = threadIdx.x & 31, y8 = threadIdx.x >> 5;
#pragma unroll
  for (int j = 0; j < 4; ++j) {
    const int y = y8 + j * 8;  // t offset
    tile[y][x] = in[(size_t)(b * NT + t0 + y) * instride + g * NHD + d0 + x];
  }
  __syncthreads();
#pragma unroll
  for (int j = 0; j < 4; ++j) {
    const int y = y8 + j * 8;  // d offset
    out[((size_t)bg * NHD + d0 + y) * NT + t0 + x] = f2b(tile[x][y]);
  }
}

// ---------- MFMA causal flash attention, 64-row Q-tiles ----------
// grid (B*H, 32). Block = 64 q-rows (4 waves x 16 rows), K-tiles of 64 keys.
// Fixed-max softmax (MFIX): no per-tile reductions, no O-rescale; one l-reduction at end.
// T14 prefetch: next K/V tile loaded to regs during compute (vmcnt drains at the
// end-of-iter barrier, so HBM/L2 latency hides under QK+softmax+PV).
// LDS strides 132/68 shorts == 2 mod 32 dwords -> even 16-bank spread (was 4-way).
// LDS 43008 B -> 3 blocks/CU.
__global__ __launch_bounds__(256, 3) void attn64(const unsigned short* __restrict__ Qh,
                                                 const unsigned short* __restrict__ Kh,
                                                 const unsigned short* __restrict__ Vtg,
                                                 unsigned short* __restrict__ O) {
  __shared__ unsigned short Kt[64 * 132];  // [key][d]
  __shared__ unsigned short Vt[128 * 68];  // [d][key]
  __shared__ unsigned short Pt[64 * 68];   // [qrow][key], wave-private 16-row slabs
  const int bh = blockIdx.x;
  const int b = bh / NH, h = bh % NH, g = h / NREP;
  const int y = blockIdx.y;
  const int a = y & 7, bb = y >> 3;
  // CU-balanced qt map: each a-group gets {a, a+8, 31-a, 23-a} (sum = 62, constant)
  const int qt = (bb == 0) ? a : (bb == 1) ? a + 8 : (bb == 2) ? 31 - a : 23 - a;
  const int tid = threadIdx.x;
  const int w = tid >> 6, lane = tid & 63;
  const int quad = lane >> 4, c = lane & 15;

  // Q A-fragments: rows qt*64 + w*16 + c, k = ch*32 + quad*8 + j
  bf16x8 qf[4];
  {
    const unsigned short* qp =
        Qh + ((size_t)(b * NH + h) * NT + qt * 64 + w * 16 + c) * NHD + quad * 8;
#pragma unroll
    for (int ch = 0; ch < 4; ++ch) qf[ch] = *(const bf16x8*)(qp + ch * 32);
  }

  f32x4 acc_o[8] = {};              // [n2]: row quad*4+r, dim n2*16+c
  float lsum[4] = {0.f, 0.f, 0.f, 0.f};
  const size_t kbase = (size_t)(b * NKVH + g) * NT * NHD;
  const size_t vbase = (size_t)(b * NKVH + g) * NHD * NT;
  const int nkt = qt + 1;

  // prologue: K/V tile 0 -> regs
  u16x8 kreg[4], vreg[4];
#pragma unroll
  for (int j = 0; j < 4; ++j) {
    const int f = j * 256 + tid;
    kreg[j] = *(const u16x8*)&Kh[kbase + (size_t)(f >> 4) * NHD + (f & 15) * 8];
    vreg[j] = *(const u16x8*)&Vtg[vbase + (size_t)(f >> 3) * NT + (f & 7) * 8];
  }

  for (int kt = 0; kt < nkt; ++kt) {
    // write staged tile to LDS
#pragma unroll
    for (int j = 0; j < 4; ++j) {
      const int f = j * 256 + tid;
      *(u16x8*)&Kt[(f >> 4) * 132 + (f & 15) * 8] = kreg[j];
      *(u16x8*)&Vt[(f >> 3) * 68 + (f & 7) * 8] = vreg[j];
    }
    __syncthreads();

    // prefetch next tile into regs (after barrier so its vmcnt isn't drained here;
    // the wait lands at the end-of-iter barrier, hidden under compute)
    if (kt + 1 < nkt) {
      const int k0 = (kt + 1) * 64;
#pragma unroll
      for (int j = 0; j < 4; ++j) {
        const int f = j * 256 + tid;
        kreg[j] = *(const u16x8*)&Kh[kbase + (size_t)(k0 + (f >> 4)) * NHD + (f & 15) * 8];
        vreg[j] = *(const u16x8*)&Vtg[vbase + (size_t)(f >> 3) * NT + k0 + (f & 7) * 8];
      }
    }

    // ---- S = Q K^T (16 x 64) ----
    f32x4 s[4] = {};
#pragma unroll
    for (int n = 0; n < 4; ++n)
#pragma unroll
      for (int ch = 0; ch < 4; ++ch) {
        bf16x8 kf = *(const bf16x8*)&Kt[(n * 16 + c) * 132 + ch * 32 + quad * 8];
        s[n] = __builtin_amdgcn_mfma_f32_16x16x32_bf16(qf[ch], kf, s[n], 0, 0, 0);
      }

    // ---- fixed-max softmax; P -> LDS (bf16) ----
    const bool dmask = (kt == qt);  // only the diagonal tile masks
#pragma unroll
    for (int r = 0; r < 4; ++r) {
      float v0 = s[0][r], v1 = s[1][r], v2 = s[2][r], v3 = s[3][r];
      const int lrow = w * 16 + quad * 4 + r;  // row within block; key offset n*16+c
      if (dmask) {
        if (c > lrow) v0 = -1e30f;
        if (16 + c > lrow) v1 = -1e30f;
        if (32 + c > lrow) v2 = -1e30f;
        if (48 + c > lrow) v3 = -1e30f;
      }
      const float p0 = __expf(v0 - MFIX), p1 = __expf(v1 - MFIX);
      const float p2 = __expf(v2 - MFIX), p3 = __expf(v3 - MFIX);
      lsum[r] += (p0 + p1) + (p2 + p3);
      Pt[lrow * 68 + c] = f2b(p0);
      Pt[lrow * 68 + 16 + c] = f2b(p1);
      Pt[lrow * 68 + 32 + c] = f2b(p2);
      Pt[lrow * 68 + 48 + c] = f2b(p3);
    }

    // ---- O += P V ----
#pragma unroll
    for (int kc2 = 0; kc2 < 2; ++kc2) {
      bf16x8 pf = *(const bf16x8*)&Pt[(w * 16 + c) * 68 + kc2 * 32 + quad * 8];
#pragma unroll
      for (int n2 = 0; n2 < 8; ++n2) {
        bf16x8 vf = *(const bf16x8*)&Vt[(n2 * 16 + c) * 68 + kc2 * 32 + quad * 8];
        acc_o[n2] = __builtin_amdgcn_mfma_f32_16x16x32_bf16(pf, vf, acc_o[n2], 0, 0, 0);
      }
    }
    __syncthreads();
  }

  // one cross-lane l reduction (within 16-lane c-group)
#pragma unroll
  for (int r = 0; r < 4; ++r) {
    float l = lsum[r];
    l += __shfl_xor(l, 1, 64);
    l += __shfl_xor(l, 2, 64);
    l += __shfl_xor(l, 4, 64);
    l += __shfl_xor(l, 8, 64);
    lsum[r] = l;
  }

#pragma unroll
  for (int r = 0; r < 4; ++r) {
    const float invl = 1.0f / lsum[r];
    const int qrow = qt * 64 + w * 16 + quad * 4 + r;
    unsigned short* op = O + ((size_t)(b * NT + qrow) * NH + h) * NHD + c;
#pragma unroll
    for (int n2 = 0; n2 < 8; ++n2) op[n2 * 16] = f2b(acc_o[n2][r] * invl);
  }
}

extern "C" void kernel_launch(void* const* d_in, const int* in_sizes, int n_in,
                              void* d_out, int out_size, void* d_ws, size_t ws_size,
                              hipStream_t stream) {
  (void)in_sizes; (void)n_in; (void)out_size; (void)ws_size;
  const float* q_input  = (const float*)d_in[0];
  const float* kv_input = (const float*)d_in[1];
  // d_in[2] = mask (static causal tril) — applied analytically
  const float* cosp = (const float*)d_in[3];
  const float* sinp = (const float*)d_in[4];
  const float* Wq = (const float*)d_in[5];
  const float* Wk = (const float*)d_in[6];
  const float* Wv = (const float*)d_in[7];
  const float* q_scale = (const float*)d_in[8];
  const float* k_scale = (const float*)d_in[9];
  const float* Wo = (const float*)d_in[10];
  float* out = (float*)d_out;

  // workspace carve (~108 MB) with lifetime-safe aliases
  char* p = (char*)d_ws;
  float* Q32  = (float*)p; p += (size_t)NB * NT * ND * 4;        // 33.5 MB
  float* KVp  = (float*)p; p += (size_t)NB * NT * 1024 * 4;      // 16.8 MB (K cols 0..511, V cols 512..1023)
  unsigned short* Qb16  = (unsigned short*)p; p += (size_t)NB * NT * ND * 2;  // 16.8 MB
  unsigned short* KVb16 = (unsigned short*)p; p += (size_t)NB * NT * ND * 2;  // 16.8 MB
  unsigned short* Kh  = (unsigned short*)p; p += (size_t)NB * NKVH * NT * NHD * 2;  // 4.2 MB
  unsigned short* Vtg = (unsigned short*)p; p += (size_t)NB * NKVH * NT * NHD * 2;  // 4.2 MB
  unsigned short* Wqt  = (unsigned short*)p; p += (size_t)ND * ND * 2;         // 8.4 MB
  unsigned short* WkvT = (unsigned short*)p; p += (size_t)1024 * ND * 2;       // 4.2 MB
  unsigned short* Wot  = (unsigned short*)p; p += (size_t)ND * ND * 2;         // 8.4 MB
  // aliases: Qb16 dead after Q-proj -> reuse as Ob; KVb16 dead after KV-proj -> reuse as Qh
  unsigned short* Ob = Qb16;
  unsigned short* Qh = KVb16;

  const dim3 blk(256);
  const int M = NB * NT;  // 4096

  // activation f32 -> bf16 (one-time)
  f2bf<<<dim3(M * ND / 2048), blk, 0, stream>>>(q_input, Qb16);
  f2bf<<<dim3(M * ND / 2048), blk, 0, stream>>>(kv_input, KVb16);

  // weight transpose+convert; Wk|Wv fused into WkvT (rows 0..511 = K, 512..1023 = V)
  wtrans<<<dim3(ND / 32, ND / 32), blk, 0, stream>>>(Wq, Wqt, ND, ND);
  wtrans<<<dim3(512 / 32, ND / 32), blk, 0, stream>>>(Wk, WkvT, ND, 512);
  wtrans<<<dim3(512 / 32, ND / 32), blk, 0, stream>>>(Wv, WkvT + (size_t)512 * ND, ND, 512);
  wtrans<<<dim3(ND / 32, ND / 32), blk, 0, stream>>>(Wo, Wot, ND, ND);

  // projections (128x128 tiles, m97 global_load_lds structure)
  gemm128<<<dim3(ND / 128, M / 128), blk, 0, stream>>>(Qb16, Wqt, Q32, M, ND, ND);
  gemm128<<<dim3(1024 / 128, M / 128), blk, 0, stream>>>(KVb16, WkvT, KVp, M, 1024, ND);

  // fixups: rmsnorm + rope + relayout; Q gets 1/sqrt(HD) folded in
  rmsnorm_rope<<<dim3(NB * NT * NH / 4), blk, 0, stream>>>(Q32, Qh, q_scale, cosp, sinp,
                                                           NH, ND, 0.08838834764831845f);
  rmsnorm_rope<<<dim3(NB * NT * NKVH / 4), blk, 0, stream>>>(KVp, Kh, k_scale, cosp, sinp,
                                                             NKVH, 1024, 1.0f);
  vtrans<<<dim3(NT / 32, NHD / 32, NB * NKVH), blk, 0, stream>>>(KVp + 512, Vtg, 1024);

  // MFMA causal GQA flash attention -> Ob (B,T,H,HD)
  attn64<<<dim3(NB * NH, 32), blk, 0, stream>>>(Qh, Kh, Vtg, Ob);

  // output projection -> d_out (f32)
  gemm128<<<dim3(ND / 128, M / 128), blk, 0, stream>>>(Ob, Wot, out, M, ND, ND);
}

// Round 3
// 385.793 us; speedup vs baseline: 1.1049x; 1.1049x over previous
//
#include <hip/hip_runtime.h>

// Problem constants (B,T,D,H,KVH fixed by the reference)
#define NB 2
#define NT 2048
#define ND 2048
#define NH 16
#define NKVH 4
#define NHD 128
#define NHALF 64
#define NREP (NH / NKVH)
#define MFIX 12.0f  // fixed softmax max: |score| <= sqrt(128) ~= 11.32 after zc-rmsnorm

typedef __bf16 bf16x8 __attribute__((ext_vector_type(8)));
typedef unsigned short u16x8 __attribute__((ext_vector_type(8)));
typedef float f32x4 __attribute__((ext_vector_type(4)));

__device__ __forceinline__ unsigned short f2b(float f) {
  union { float f; unsigned int u; } v; v.f = f;
  unsigned int r = v.u + 0x7FFFu + ((v.u >> 16) & 1u);
  return (unsigned short)(r >> 16);
}
__device__ __forceinline__ float b2f(unsigned short h) {
  union { unsigned int u; float f; } v; v.u = ((unsigned int)h) << 16;
  return v.f;
}

// async global->LDS DMA, 16B per lane. LDS dest = wave-uniform base + lane*16.
__device__ __forceinline__ void glds16(const unsigned short* g, unsigned short* l) {
  __builtin_amdgcn_global_load_lds(
      (__attribute__((address_space(1))) unsigned int*)(unsigned long long)g,
      (__attribute__((address_space(3))) unsigned int*)(unsigned int)(unsigned long long)l,
      16, 0, 0);
}

// ---------- f32 -> bf16 elementwise (8/thread) ----------
__global__ __launch_bounds__(256) void f2bf(const float* __restrict__ in,
                                            unsigned short* __restrict__ out) {
  const size_t i = (size_t)(blockIdx.x * 256 + threadIdx.x) * 8;
  float4 a = *(const float4*)(in + i);
  float4 b = *(const float4*)(in + i + 4);
  u16x8 r;
  r[0] = f2b(a.x); r[1] = f2b(a.y); r[2] = f2b(a.z); r[3] = f2b(a.w);
  r[4] = f2b(b.x); r[5] = f2b(b.y); r[6] = f2b(b.z); r[7] = f2b(b.w);
  *(u16x8*)(out + i) = r;
}

// ---------- weight transpose + convert: in (K,N) f32 -> out (N,K) bf16 ----------
__global__ __launch_bounds__(256) void wtrans(const float* __restrict__ in,
                                              unsigned short* __restrict__ out,
                                              int K, int N) {
  __shared__ float tile[32][33];
  const int k0 = blockIdx.y * 32, n0 = blockIdx.x * 32;
  const int x = threadIdx.x & 31, y8 = threadIdx.x >> 5;
#pragma unroll
  for (int j = 0; j < 4; ++j) {
    const int y = y8 + j * 8;
    tile[y][x] = in[(size_t)(k0 + y) * N + n0 + x];
  }
  __syncthreads();
#pragma unroll
  for (int j = 0; j < 4; ++j) {
    const int y = y8 + j * 8;
    out[(size_t)(n0 + y) * K + k0 + x] = f2b(tile[x][y]);
  }
}

// ---------- MFMA GEMM: C(M,N) f32 = A(M,K)bf16 @ Bt(N,K)bf16^T ----------
// 128x128 tile, BK=32. 2-phase double-buffered pipeline with global_load_lds:
// next K-step's glds issued BEFORE compute; __syncthreads() at end of step
// provides exactly the needed semantics (drain own vmcnt, then barrier) and
// is a real compiler fence (raw s_barrier is NOT — r2 hang suspect).
// One barrier per K-step; vmcnt drain lands AFTER the MFMA phase.
// T1 XCD-aware swizzle on the linearized block index (all grids %8 == 0).
__global__ __launch_bounds__(256) void gemm128(const unsigned short* __restrict__ A,
                                               const unsigned short* __restrict__ Bt,
                                               float* __restrict__ C,
                                               int M, int N, int K) {
  __shared__ unsigned short As[2][128 * 32];
  __shared__ unsigned short Bs[2][128 * 32];
  const int tid = threadIdx.x;
  const int wave = tid >> 6, lane = tid & 63;
  const int wm = wave >> 1, wn = wave & 1;
  const int quad = lane >> 4, c = lane & 15;

  // XCD swizzle: contiguous chunk of tile space per XCD (bijective: nwg%8==0)
  const int gx = gridDim.x;
  const int nwg = gx * gridDim.y;
  int lin = blockIdx.y * gx + blockIdx.x;
  lin = (lin & 7) * (nwg >> 3) + (lin >> 3);
  const int m0 = (lin / gx) * 128, n0 = (lin % gx) * 128;

  // per-lane global sources; wave-uniform LDS dests (base + lane*16 implicit)
  const unsigned short* pa0 = A + (size_t)(m0 + wave * 16 + (lane >> 2)) * K + (lane & 3) * 8;
  const unsigned short* pa1 = pa0 + (size_t)64 * K;
  const unsigned short* pb0 = Bt + (size_t)(n0 + wave * 16 + (lane >> 2)) * K + (lane & 3) * 8;
  const unsigned short* pb1 = pb0 + (size_t)64 * K;

  f32x4 acc[4][4] = {};

  const int nsteps = K >> 5;
  int cur = 0;
  // prologue: stage tile 0 into buf 0
  glds16(pa0, &As[0][(wave * 16) * 32]);
  glds16(pa1, &As[0][(64 + wave * 16) * 32]);
  glds16(pb0, &Bs[0][(wave * 16) * 32]);
  glds16(pb1, &Bs[0][(64 + wave * 16) * 32]);
  __syncthreads();

  for (int t = 0; t < nsteps; ++t) {
    // issue next tile's loads into the other buffer (latency hides under MFMA)
    if (t + 1 < nsteps) {
      const int kn = (t + 1) << 5;
      glds16(pa0 + kn, &As[cur ^ 1][(wave * 16) * 32]);
      glds16(pa1 + kn, &As[cur ^ 1][(64 + wave * 16) * 32]);
      glds16(pb0 + kn, &Bs[cur ^ 1][(wave * 16) * 32]);
      glds16(pb1 + kn, &Bs[cur ^ 1][(64 + wave * 16) * 32]);
    }
    bf16x8 af[4];
#pragma unroll
    for (int sm = 0; sm < 4; ++sm)
      af[sm] = *(const bf16x8*)&As[cur][(wm * 64 + sm * 16 + c) * 32 + quad * 8];
#pragma unroll
    for (int sn = 0; sn < 4; ++sn) {
      bf16x8 bfr = *(const bf16x8*)&Bs[cur][(wn * 64 + sn * 16 + c) * 32 + quad * 8];
#pragma unroll
      for (int sm = 0; sm < 4; ++sm)
        acc[sm][sn] = __builtin_amdgcn_mfma_f32_16x16x32_bf16(af[sm], bfr, acc[sm][sn], 0, 0, 0);
    }
    // drain own glds (vmcnt) + join: next buffer globally ready after this.
    // All reads of buf[cur] happened above, so flipping is safe.
    __syncthreads();
    cur ^= 1;
  }

#pragma unroll
  for (int sm = 0; sm < 4; ++sm)
#pragma unroll
    for (int sn = 0; sn < 4; ++sn) {
      const int row = m0 + wm * 64 + sm * 16 + quad * 4;
      const int col = n0 + wn * 64 + sn * 16 + c;
#pragma unroll
      for (int r = 0; r < 4; ++r)
        C[(size_t)(row + r) * N + col] = acc[sm][sn][r];
    }
}

// ---------- fused zc-RMSNorm + RoPE; rows (b,t,h) -> (B,nh,T,HD) bf16 ----------
__global__ __launch_bounds__(256) void rmsnorm_rope(const float* __restrict__ in,
                                                    unsigned short* __restrict__ out,
                                                    const float* __restrict__ scale,
                                                    const float* __restrict__ cosp,
                                                    const float* __restrict__ sinp,
                                                    int nh, int instride, float outscale) {
  const int wid = blockIdx.x * 4 + (threadIdx.x >> 6);
  const int lane = threadIdx.x & 63;
  const int h = wid % nh;
  const int t = (wid / nh) % NT;
  const int b = wid / (nh * NT);
  const float* x = in + (size_t)(b * NT + t) * instride + h * NHD;
  float x1 = x[lane], x2 = x[lane + NHALF];
  float ss = x1 * x1 + x2 * x2;
#pragma unroll
  for (int m = 1; m < 64; m <<= 1) ss += __shfl_xor(ss, m, 64);
  const float inv = 1.0f / sqrtf(ss * (1.0f / NHD) + 1e-6f);
  const float n1 = (1.0f + scale[lane]) * x1 * inv;
  const float n2 = (1.0f + scale[lane + NHALF]) * x2 * inv;
  const float cc = cosp[t * NHALF + lane], s = sinp[t * NHALF + lane];
  const size_t ob = (((size_t)b * nh + h) * NT + t) * NHD;
  out[ob + lane] = f2b((n1 * cc - n2 * s) * outscale);
  out[ob + lane + NHALF] = f2b((n2 * cc + n1 * s) * outscale);
}

// ---------- V transpose: rows (b,t) f32 -> (B,KVH,HD,T) bf16 ----------
__global__ __launch_bounds__(256) void vtrans(const float* __restrict__ in,
                                              unsigned short* __restrict__ out,
                                              int instride) {
  __shared__ float tile[32][33];
  const int bg = blockIdx.z;  // b*NKVH + g
  const int b = bg >> 2, g = bg & 3;
  const int t0 = blockIdx.x * 32, d0 = blockIdx.y * 32;
  const int x = threadIdx.x & 31, y8 = threadIdx.x >> 5;
#pragma unroll
  for (int j = 0; j < 4; ++j) {
    const int y = y8 + j * 8;  // t offset
    tile[y][x] = in[(size_t)(b * NT + t0 + y) * instride + g * NHD + d0 + x];
  }
  __syncthreads();
#pragma unroll
  for (int j = 0; j < 4; ++j) {
    const int y = y8 + j * 8;  // d offset
    out[((size_t)bg * NHD + d0 + y) * NT + t0 + x] = f2b(tile[x][y]);
  }
}

// ---------- MFMA causal flash attention, 64-row Q-tiles ----------
// grid (B*H, 32). Block = 64 q-rows (4 waves x 16 rows), K-tiles of 64 keys.
// Fixed-max softmax (MFIX): no per-tile reductions, no O-rescale; one l-reduction at end.
// T14 prefetch: next K/V tile loaded to regs during compute.
// LDS strides 132/68 shorts; LDS 43008 B -> 3 blocks/CU.
__global__ __launch_bounds__(256, 3) void attn64(const unsigned short* __restrict__ Qh,
                                                 const unsigned short* __restrict__ Kh,
                                                 const unsigned short* __restrict__ Vtg,
                                                 unsigned short* __restrict__ O) {
  __shared__ unsigned short Kt[64 * 132];  // [key][d]
  __shared__ unsigned short Vt[128 * 68];  // [d][key]
  __shared__ unsigned short Pt[64 * 68];   // [qrow][key], wave-private 16-row slabs
  const int bh = blockIdx.x;
  const int b = bh / NH, h = bh % NH, g = h / NREP;
  const int y = blockIdx.y;
  const int a = y & 7, bb = y >> 3;
  // CU-balanced qt map: each a-group gets {a, a+8, 31-a, 23-a} (sum = 62, constant)
  const int qt = (bb == 0) ? a : (bb == 1) ? a + 8 : (bb == 2) ? 31 - a : 23 - a;
  const int tid = threadIdx.x;
  const int w = tid >> 6, lane = tid & 63;
  const int quad = lane >> 4, c = lane & 15;

  // Q A-fragments: rows qt*64 + w*16 + c, k = ch*32 + quad*8 + j
  bf16x8 qf[4];
  {
    const unsigned short* qp =
        Qh + ((size_t)(b * NH + h) * NT + qt * 64 + w * 16 + c) * NHD + quad * 8;
#pragma unroll
    for (int ch = 0; ch < 4; ++ch) qf[ch] = *(const bf16x8*)(qp + ch * 32);
  }

  f32x4 acc_o[8] = {};              // [n2]: row quad*4+r, dim n2*16+c
  float lsum[4] = {0.f, 0.f, 0.f, 0.f};
  const size_t kbase = (size_t)(b * NKVH + g) * NT * NHD;
  const size_t vbase = (size_t)(b * NKVH + g) * NHD * NT;
  const int nkt = qt + 1;

  // prologue: K/V tile 0 -> regs
  u16x8 kreg[4], vreg[4];
#pragma unroll
  for (int j = 0; j < 4; ++j) {
    const int f = j * 256 + tid;
    kreg[j] = *(const u16x8*)&Kh[kbase + (size_t)(f >> 4) * NHD + (f & 15) * 8];
    vreg[j] = *(const u16x8*)&Vtg[vbase + (size_t)(f >> 3) * NT + (f & 7) * 8];
  }

  for (int kt = 0; kt < nkt; ++kt) {
    // write staged tile to LDS
#pragma unroll
    for (int j = 0; j < 4; ++j) {
      const int f = j * 256 + tid;
      *(u16x8*)&Kt[(f >> 4) * 132 + (f & 15) * 8] = kreg[j];
      *(u16x8*)&Vt[(f >> 3) * 68 + (f & 7) * 8] = vreg[j];
    }
    __syncthreads();

    // prefetch next tile into regs (vmcnt drains at end-of-iter barrier,
    // hidden under QK+softmax+PV)
    if (kt + 1 < nkt) {
      const int k0 = (kt + 1) * 64;
#pragma unroll
      for (int j = 0; j < 4; ++j) {
        const int f = j * 256 + tid;
        kreg[j] = *(const u16x8*)&Kh[kbase + (size_t)(k0 + (f >> 4)) * NHD + (f & 15) * 8];
        vreg[j] = *(const u16x8*)&Vtg[vbase + (size_t)(f >> 3) * NT + k0 + (f & 7) * 8];
      }
    }

    // ---- S = Q K^T (16 x 64) ----
    f32x4 s[4] = {};
#pragma unroll
    for (int n = 0; n < 4; ++n)
#pragma unroll
      for (int ch = 0; ch < 4; ++ch) {
        bf16x8 kf = *(const bf16x8*)&Kt[(n * 16 + c) * 132 + ch * 32 + quad * 8];
        s[n] = __builtin_amdgcn_mfma_f32_16x16x32_bf16(qf[ch], kf, s[n], 0, 0, 0);
      }

    // ---- fixed-max softmax; P -> LDS (bf16) ----
    const bool dmask = (kt == qt);  // only the diagonal tile masks
#pragma unroll
    for (int r = 0; r < 4; ++r) {
      float v0 = s[0][r], v1 = s[1][r], v2 = s[2][r], v3 = s[3][r];
      const int lrow = w * 16 + quad * 4 + r;  // row within block; key offset n*16+c
      if (dmask) {
        if (c > lrow) v0 = -1e30f;
        if (16 + c > lrow) v1 = -1e30f;
        if (32 + c > lrow) v2 = -1e30f;
        if (48 + c > lrow) v3 = -1e30f;
      }
      const float p0 = __expf(v0 - MFIX), p1 = __expf(v1 - MFIX);
      const float p2 = __expf(v2 - MFIX), p3 = __expf(v3 - MFIX);
      lsum[r] += (p0 + p1) + (p2 + p3);
      Pt[lrow * 68 + c] = f2b(p0);
      Pt[lrow * 68 + 16 + c] = f2b(p1);
      Pt[lrow * 68 + 32 + c] = f2b(p2);
      Pt[lrow * 68 + 48 + c] = f2b(p3);
    }

    // ---- O += P V ----
#pragma unroll
    for (int kc2 = 0; kc2 < 2; ++kc2) {
      bf16x8 pf = *(const bf16x8*)&Pt[(w * 16 + c) * 68 + kc2 * 32 + quad * 8];
#pragma unroll
      for (int n2 = 0; n2 < 8; ++n2) {
        bf16x8 vf = *(const bf16x8*)&Vt[(n2 * 16 + c) * 68 + kc2 * 32 + quad * 8];
        acc_o[n2] = __builtin_amdgcn_mfma_f32_16x16x32_bf16(pf, vf, acc_o[n2], 0, 0, 0);
      }
    }
    __syncthreads();
  }

  // one cross-lane l reduction (within 16-lane c-group)
#pragma unroll
  for (int r = 0; r < 4; ++r) {
    float l = lsum[r];
    l += __shfl_xor(l, 1, 64);
    l += __shfl_xor(l, 2, 64);
    l += __shfl_xor(l, 4, 64);
    l += __shfl_xor(l, 8, 64);
    lsum[r] = l;
  }

#pragma unroll
  for (int r = 0; r < 4; ++r) {
    const float invl = 1.0f / lsum[r];
    const int qrow = qt * 64 + w * 16 + quad * 4 + r;
    unsigned short* op = O + ((size_t)(b * NT + qrow) * NH + h) * NHD + c;
#pragma unroll
    for (int n2 = 0; n2 < 8; ++n2) op[n2 * 16] = f2b(acc_o[n2][r] * invl);
  }
}

extern "C" void kernel_launch(void* const* d_in, const int* in_sizes, int n_in,
                              void* d_out, int out_size, void* d_ws, size_t ws_size,
                              hipStream_t stream) {
  (void)in_sizes; (void)n_in; (void)out_size; (void)ws_size;
  const float* q_input  = (const float*)d_in[0];
  const float* kv_input = (const float*)d_in[1];
  // d_in[2] = mask (static causal tril) — applied analytically
  const float* cosp = (const float*)d_in[3];
  const float* sinp = (const float*)d_in[4];
  const float* Wq = (const float*)d_in[5];
  const float* Wk = (const float*)d_in[6];
  const float* Wv = (const float*)d_in[7];
  const float* q_scale = (const float*)d_in[8];
  const float* k_scale = (const float*)d_in[9];
  const float* Wo = (const float*)d_in[10];
  float* out = (float*)d_out;

  // workspace carve (~108 MB) with lifetime-safe aliases
  char* p = (char*)d_ws;
  float* Q32  = (float*)p; p += (size_t)NB * NT * ND * 4;        // 33.5 MB
  float* KVp  = (float*)p; p += (size_t)NB * NT * 1024 * 4;      // 16.8 MB (K cols 0..511, V cols 512..1023)
  unsigned short* Qb16  = (unsigned short*)p; p += (size_t)NB * NT * ND * 2;  // 16.8 MB
  unsigned short* KVb16 = (unsigned short*)p; p += (size_t)NB * NT * ND * 2;  // 16.8 MB
  unsigned short* Kh  = (unsigned short*)p; p += (size_t)NB * NKVH * NT * NHD * 2;  // 4.2 MB
  unsigned short* Vtg = (unsigned short*)p; p += (size_t)NB * NKVH * NT * NHD * 2;  // 4.2 MB
  unsigned short* Wqt  = (unsigned short*)p; p += (size_t)ND * ND * 2;         // 8.4 MB
  unsigned short* WkvT = (unsigned short*)p; p += (size_t)1024 * ND * 2;       // 4.2 MB
  unsigned short* Wot  = (unsigned short*)p; p += (size_t)ND * ND * 2;         // 8.4 MB
  // aliases: Qb16 dead after Q-proj -> reuse as Ob; KVb16 dead after KV-proj -> reuse as Qh
  unsigned short* Ob = Qb16;
  unsigned short* Qh = KVb16;

  const dim3 blk(256);
  const int M = NB * NT;  // 4096

  // activation f32 -> bf16 (one-time)
  f2bf<<<dim3(M * ND / 2048), blk, 0, stream>>>(q_input, Qb16);
  f2bf<<<dim3(M * ND / 2048), blk, 0, stream>>>(kv_input, KVb16);

  // weight transpose+convert; Wk|Wv fused into WkvT (rows 0..511 = K, 512..1023 = V)
  wtrans<<<dim3(ND / 32, ND / 32), blk, 0, stream>>>(Wq, Wqt, ND, ND);
  wtrans<<<dim3(512 / 32, ND / 32), blk, 0, stream>>>(Wk, WkvT, ND, 512);
  wtrans<<<dim3(512 / 32, ND / 32), blk, 0, stream>>>(Wv, WkvT + (size_t)512 * ND, ND, 512);
  wtrans<<<dim3(ND / 32, ND / 32), blk, 0, stream>>>(Wo, Wot, ND, ND);

  // projections (128x128 tiles, 2-phase dbuf global_load_lds pipeline)
  gemm128<<<dim3(ND / 128, M / 128), blk, 0, stream>>>(Qb16, Wqt, Q32, M, ND, ND);
  gemm128<<<dim3(1024 / 128, M / 128), blk, 0, stream>>>(KVb16, WkvT, KVp, M, 1024, ND);

  // fixups: rmsnorm + rope + relayout; Q gets 1/sqrt(HD) folded in
  rmsnorm_rope<<<dim3(NB * NT * NH / 4), blk, 0, stream>>>(Q32, Qh, q_scale, cosp, sinp,
                                                           NH, ND, 0.08838834764831845f);
  rmsnorm_rope<<<dim3(NB * NT * NKVH / 4), blk, 0, stream>>>(KVp, Kh, k_scale, cosp, sinp,
                                                             NKVH, 1024, 1.0f);
  vtrans<<<dim3(NT / 32, NHD / 32, NB * NKVH), blk, 0, stream>>>(KVp + 512, Vtg, 1024);

  // MFMA causal GQA flash attention -> Ob (B,T,H,HD)
  attn64<<<dim3(NB * NH, 32), blk, 0, stream>>>(Qh, Kh, Vtg, Ob);

  // output projection -> d_out (f32)
  gemm128<<<dim3(ND / 128, M / 128), blk, 0, stream>>>(Ob, Wot, out, M, ND, ND);
}

// Round 4
// 366.433 us; speedup vs baseline: 1.1633x; 1.0528x over previous
//
#include <hip/hip_runtime.h>

// Problem constants (B,T,D,H,KVH fixed by the reference)
#define NB 2
#define NT 2048
#define ND 2048
#define NH 16
#define NKVH 4
#define NHD 128
#define NHALF 64
#define NREP (NH / NKVH)
#define MFIX 12.0f  // fixed softmax max: |score| <= sqrt(128) ~= 11.32 after zc-rmsnorm

typedef __bf16 bf16x8 __attribute__((ext_vector_type(8)));
typedef unsigned short u16x8 __attribute__((ext_vector_type(8)));
typedef float f32x4 __attribute__((ext_vector_type(4)));

__device__ __forceinline__ unsigned short f2b(float f) {
  union { float f; unsigned int u; } v; v.f = f;
  unsigned int r = v.u + 0x7FFFu + ((v.u >> 16) & 1u);
  return (unsigned short)(r >> 16);
}
__device__ __forceinline__ float b2f(unsigned short h) {
  union { unsigned int u; float f; } v; v.u = ((unsigned int)h) << 16;
  return v.f;
}

// async global->LDS DMA, 16B per lane. LDS dest = wave-uniform base + lane*16.
__device__ __forceinline__ void glds16(const unsigned short* g, unsigned short* l) {
  __builtin_amdgcn_global_load_lds(
      (__attribute__((address_space(1))) unsigned int*)(unsigned long long)g,
      (__attribute__((address_space(3))) unsigned int*)(unsigned int)(unsigned long long)l,
      16, 0, 0);
}

// ---------- f32 -> bf16 elementwise (8/thread) ----------
__global__ __launch_bounds__(256) void f2bf(const float* __restrict__ in,
                                            unsigned short* __restrict__ out) {
  const size_t i = (size_t)(blockIdx.x * 256 + threadIdx.x) * 8;
  float4 a = *(const float4*)(in + i);
  float4 b = *(const float4*)(in + i + 4);
  u16x8 r;
  r[0] = f2b(a.x); r[1] = f2b(a.y); r[2] = f2b(a.z); r[3] = f2b(a.w);
  r[4] = f2b(b.x); r[5] = f2b(b.y); r[6] = f2b(b.z); r[7] = f2b(b.w);
  *(u16x8*)(out + i) = r;
}

// ---------- weight transpose + convert: in (K,N) f32 -> out (N,K) bf16 ----------
__global__ __launch_bounds__(256) void wtrans(const float* __restrict__ in,
                                              unsigned short* __restrict__ out,
                                              int K, int N) {
  __shared__ float tile[32][33];
  const int k0 = blockIdx.y * 32, n0 = blockIdx.x * 32;
  const int x = threadIdx.x & 31, y8 = threadIdx.x >> 5;
#pragma unroll
  for (int j = 0; j < 4; ++j) {
    const int y = y8 + j * 8;
    tile[y][x] = in[(size_t)(k0 + y) * N + n0 + x];
  }
  __syncthreads();
#pragma unroll
  for (int j = 0; j < 4; ++j) {
    const int y = y8 + j * 8;
    out[(size_t)(n0 + y) * K + k0 + x] = f2b(tile[x][y]);
  }
}

// ---------- GEMM core: C(:,N) tile (m0,n0) = A(M,K)bf16 @ Bt(N,K)bf16^T ----------
// 128x128 tile, BK=64, 2-phase double-buffered global_load_lds pipeline.
// LDS layout is LINEAR [128][64] (glds requires contiguous dest); bank-conflict
// freedom comes from XOR-granule swizzle applied on BOTH sides (rule #21):
//   - staging: lane fetches global 16B-granule ((lane&7) ^ (lane>>3)) of its row
//   - reading: fragment at data-granule g is read from LDS granule g ^ (row&7)
// Every consecutive-8-lane group then covers all 8 granules -> all 32 banks.
// 32 MFMA between barriers (2x r3); one __syncthreads per K-step (own-vmcnt
// drain + join, a real compiler fence).
__device__ __forceinline__ void gemm_core(const unsigned short* __restrict__ A,
                                          const unsigned short* __restrict__ Bt,
                                          float* __restrict__ C,
                                          int N, int K, int m0, int n0,
                                          unsigned short* As, unsigned short* Bs) {
  const int tid = threadIdx.x;
  const int wave = tid >> 6, lane = tid & 63;
  const int wm = wave >> 1, wn = wave & 1;
  const int quad = lane >> 4, c = lane & 15;
  const int lr = lane >> 3;                 // 0..7: row within an 8-row stage group
  const int gsw = ((lane & 7) ^ lr) * 8;    // pre-swizzled source granule (shorts)

  const unsigned short* pa[4];
  const unsigned short* pb[4];
  unsigned short* da[4];
  unsigned short* db[4];
#pragma unroll
  for (int j = 0; j < 4; ++j) {
    const int rb = j * 32 + wave * 8;       // 8-row group base (multiple of 8)
    pa[j] = A + (size_t)(m0 + rb + lr) * K + gsw;
    pb[j] = Bt + (size_t)(n0 + rb + lr) * K + gsw;
    da[j] = As + rb * 64;
    db[j] = Bs + rb * 64;
  }

  f32x4 acc[4][4] = {};
  const int nsteps = K >> 6;
  int cur = 0;

  // prologue: stage K-step 0 into buffer 0
#pragma unroll
  for (int j = 0; j < 4; ++j) { glds16(pa[j], da[j]); glds16(pb[j], db[j]); }
  __syncthreads();

  for (int t = 0; t < nsteps; ++t) {
    const int nxt = (cur ^ 1) * (128 * 64);
    if (t + 1 < nsteps) {  // issue next K-step's DMA; latency hides under MFMA
      const int kn = (t + 1) << 6;
#pragma unroll
      for (int j = 0; j < 4; ++j) {
        glds16(pa[j] + kn, da[j] + nxt);
        glds16(pb[j] + kn, db[j] + nxt);
      }
    }
    const unsigned short* Ab = As + cur * (128 * 64);
    const unsigned short* Bb = Bs + cur * (128 * 64);
#pragma unroll
    for (int kk = 0; kk < 2; ++kk) {
      const int g = ((kk * 4 + quad) ^ (c & 7)) * 8;  // swizzled read granule
      bf16x8 af[4];
#pragma unroll
      for (int sm = 0; sm < 4; ++sm)
        af[sm] = *(const bf16x8*)&Ab[(wm * 64 + sm * 16 + c) * 64 + g];
#pragma unroll
      for (int sn = 0; sn < 4; ++sn) {
        bf16x8 bfr = *(const bf16x8*)&Bb[(wn * 64 + sn * 16 + c) * 64 + g];
#pragma unroll
        for (int sm = 0; sm < 4; ++sm)
          acc[sm][sn] = __builtin_amdgcn_mfma_f32_16x16x32_bf16(af[sm], bfr, acc[sm][sn], 0, 0, 0);
      }
    }
    // drain own glds (vmcnt) + join: next buffer globally ready; all reads of
    // buf[cur] happened above, so flipping is safe.
    __syncthreads();
    cur ^= 1;
  }

#pragma unroll
  for (int sm = 0; sm < 4; ++sm)
#pragma unroll
    for (int sn = 0; sn < 4; ++sn) {
      const int row = m0 + wm * 64 + sm * 16 + quad * 4;
      const int col = n0 + wn * 64 + sn * 16 + c;
#pragma unroll
      for (int r = 0; r < 4; ++r)
        C[(size_t)(row + r) * N + col] = acc[sm][sn][r];
    }
}

// ---------- standalone GEMM (O-projection) ----------
__global__ __launch_bounds__(256) void gemm128(const unsigned short* __restrict__ A,
                                               const unsigned short* __restrict__ Bt,
                                               float* __restrict__ C,
                                               int M, int N, int K) {
  __shared__ unsigned short As[2 * 128 * 64];
  __shared__ unsigned short Bs[2 * 128 * 64];
  // T1 XCD swizzle (bijective: nwg % 8 == 0 for all our grids)
  const int gx = gridDim.x;
  const int nwg = gx * gridDim.y;
  int lin = blockIdx.y * gx + blockIdx.x;
  lin = (lin & 7) * (nwg >> 3) + (lin >> 3);
  gemm_core(A, Bt, C, N, K, (lin / gx) * 128, (lin % gx) * 128, As, Bs);
}

// ---------- fused Q-proj + KV-proj in one dispatch (768 blocks) ----------
// Stream serialization otherwise prevents the 256-block KV-proj (1 block/CU!)
// from overlapping the Q-proj tail. Block-uniform branch -> barriers safe.
__global__ __launch_bounds__(256) void gemm_qkv(const unsigned short* __restrict__ Aq,
                                                const unsigned short* __restrict__ Wq,
                                                float* __restrict__ Cq,
                                                const unsigned short* __restrict__ Akv,
                                                const unsigned short* __restrict__ Wkv,
                                                float* __restrict__ Ckv) {
  __shared__ unsigned short As[2 * 128 * 64];
  __shared__ unsigned short Bs[2 * 128 * 64];
  int lin = blockIdx.x;
  lin = (lin & 7) * 96 + (lin >> 3);  // nwg = 768
  if (lin < 512) {
    gemm_core(Aq, Wq, Cq, 2048, 2048, (lin >> 4) * 128, (lin & 15) * 128, As, Bs);
  } else {
    const int l2 = lin - 512;
    gemm_core(Akv, Wkv, Ckv, 1024, 2048, (l2 >> 3) * 128, (l2 & 7) * 128, As, Bs);
  }
}

// ---------- fused zc-RMSNorm + RoPE; rows (b,t,h) -> (B,nh,T,HD) bf16 ----------
__global__ __launch_bounds__(256) void rmsnorm_rope(const float* __restrict__ in,
                                                    unsigned short* __restrict__ out,
                                                    const float* __restrict__ scale,
                                                    const float* __restrict__ cosp,
                                                    const float* __restrict__ sinp,
                                                    int nh, int instride, float outscale) {
  const int wid = blockIdx.x * 4 + (threadIdx.x >> 6);
  const int lane = threadIdx.x & 63;
  const int h = wid % nh;
  const int t = (wid / nh) % NT;
  const int b = wid / (nh * NT);
  const float* x = in + (size_t)(b * NT + t) * instride + h * NHD;
  float x1 = x[lane], x2 = x[lane + NHALF];
  float ss = x1 * x1 + x2 * x2;
#pragma unroll
  for (int m = 1; m < 64; m <<= 1) ss += __shfl_xor(ss, m, 64);
  const float inv = 1.0f / sqrtf(ss * (1.0f / NHD) + 1e-6f);
  const float n1 = (1.0f + scale[lane]) * x1 * inv;
  const float n2 = (1.0f + scale[lane + NHALF]) * x2 * inv;
  const float cc = cosp[t * NHALF + lane], s = sinp[t * NHALF + lane];
  const size_t ob = (((size_t)b * nh + h) * NT + t) * NHD;
  out[ob + lane] = f2b((n1 * cc - n2 * s) * outscale);
  out[ob + lane + NHALF] = f2b((n2 * cc + n1 * s) * outscale);
}

// ---------- V transpose: rows (b,t) f32 -> (B,KVH,HD,T) bf16 ----------
__global__ __launch_bounds__(256) void vtrans(const float* __restrict__ in,
                                              unsigned short* __restrict__ out,
                                              int instride) {
  __shared__ float tile[32][33];
  const int bg = blockIdx.z;  // b*NKVH + g
  const int b = bg >> 2, g = bg & 3;
  const int t0 = blockIdx.x * 32, d0 = blockIdx.y * 32;
  const int x = threadIdx.x & 31, y8 = threadIdx.x >> 5;
#pragma unroll
  for (int j = 0; j < 4; ++j) {
    const int y = y8 + j * 8;  // t offset
    tile[y][x] = in[(size_t)(b * NT + t0 + y) * instride + g * NHD + d0 + x];
  }
  __syncthreads();
#pragma unroll
  for (int j = 0; j < 4; ++j) {
    const int y = y8 + j * 8;  // d offset
    out[((size_t)bg * NHD + d0 + y) * NT + t0 + x] = f2b(tile[x][y]);
  }
}

// ---------- MFMA causal flash attention, 64-row Q-tiles ----------
// grid (B*H, 32). Block = 64 q-rows (4 waves x 16 rows), K-tiles of 64 keys.
// Fixed-max softmax (MFIX): no per-tile reductions, no O-rescale; one l-reduction at end.
// T14 prefetch: next K/V tile loaded to regs during compute.
// LDS strides 132/68 shorts; LDS 43008 B -> 3 blocks/CU.
__global__ __launch_bounds__(256, 3) void attn64(const unsigned short* __restrict__ Qh,
                                                 const unsigned short* __restrict__ Kh,
                                                 const unsigned short* __restrict__ Vtg,
                                                 unsigned short* __restrict__ O) {
  __shared__ unsigned short Kt[64 * 132];  // [key][d]
  __shared__ unsigned short Vt[128 * 68];  // [d][key]
  __shared__ unsigned short Pt[64 * 68];   // [qrow][key], wave-private 16-row slabs
  const int bh = blockIdx.x;
  const int b = bh / NH, h = bh % NH, g = h / NREP;
  const int y = blockIdx.y;
  const int a = y & 7, bb = y >> 3;
  // CU-balanced qt map: each a-group gets {a, a+8, 31-a, 23-a} (sum = 62, constant)
  const int qt = (bb == 0) ? a : (bb == 1) ? a + 8 : (bb == 2) ? 31 - a : 23 - a;
  const int tid = threadIdx.x;
  const int w = tid >> 6, lane = tid & 63;
  const int quad = lane >> 4, c = lane & 15;

  // Q A-fragments: rows qt*64 + w*16 + c, k = ch*32 + quad*8 + j
  bf16x8 qf[4];
  {
    const unsigned short* qp =
        Qh + ((size_t)(b * NH + h) * NT + qt * 64 + w * 16 + c) * NHD + quad * 8;
#pragma unroll
    for (int ch = 0; ch < 4; ++ch) qf[ch] = *(const bf16x8*)(qp + ch * 32);
  }

  f32x4 acc_o[8] = {};              // [n2]: row quad*4+r, dim n2*16+c
  float lsum[4] = {0.f, 0.f, 0.f, 0.f};
  const size_t kbase = (size_t)(b * NKVH + g) * NT * NHD;
  const size_t vbase = (size_t)(b * NKVH + g) * NHD * NT;
  const int nkt = qt + 1;

  // prologue: K/V tile 0 -> regs
  u16x8 kreg[4], vreg[4];
#pragma unroll
  for (int j = 0; j < 4; ++j) {
    const int f = j * 256 + tid;
    kreg[j] = *(const u16x8*)&Kh[kbase + (size_t)(f >> 4) * NHD + (f & 15) * 8];
    vreg[j] = *(const u16x8*)&Vtg[vbase + (size_t)(f >> 3) * NT + (f & 7) * 8];
  }

  for (int kt = 0; kt < nkt; ++kt) {
    // write staged tile to LDS
#pragma unroll
    for (int j = 0; j < 4; ++j) {
      const int f = j * 256 + tid;
      *(u16x8*)&Kt[(f >> 4) * 132 + (f & 15) * 8] = kreg[j];
      *(u16x8*)&Vt[(f >> 3) * 68 + (f & 7) * 8] = vreg[j];
    }
    __syncthreads();

    // prefetch next tile into regs (vmcnt drains at end-of-iter barrier,
    // hidden under QK+softmax+PV)
    if (kt + 1 < nkt) {
      const int k0 = (kt + 1) * 64;
#pragma unroll
      for (int j = 0; j < 4; ++j) {
        const int f = j * 256 + tid;
        kreg[j] = *(const u16x8*)&Kh[kbase + (size_t)(k0 + (f >> 4)) * NHD + (f & 15) * 8];
        vreg[j] = *(const u16x8*)&Vtg[vbase + (size_t)(f >> 3) * NT + k0 + (f & 7) * 8];
      }
    }

    // ---- S = Q K^T (16 x 64) ----
    f32x4 s[4] = {};
#pragma unroll
    for (int n = 0; n < 4; ++n)
#pragma unroll
      for (int ch = 0; ch < 4; ++ch) {
        bf16x8 kf = *(const bf16x8*)&Kt[(n * 16 + c) * 132 + ch * 32 + quad * 8];
        s[n] = __builtin_amdgcn_mfma_f32_16x16x32_bf16(qf[ch], kf, s[n], 0, 0, 0);
      }

    // ---- fixed-max softmax; P -> LDS (bf16) ----
    const bool dmask = (kt == qt);  // only the diagonal tile masks
#pragma unroll
    for (int r = 0; r < 4; ++r) {
      float v0 = s[0][r], v1 = s[1][r], v2 = s[2][r], v3 = s[3][r];
      const int lrow = w * 16 + quad * 4 + r;  // row within block; key offset n*16+c
      if (dmask) {
        if (c > lrow) v0 = -1e30f;
        if (16 + c > lrow) v1 = -1e30f;
        if (32 + c > lrow) v2 = -1e30f;
        if (48 + c > lrow) v3 = -1e30f;
      }
      const float p0 = __expf(v0 - MFIX), p1 = __expf(v1 - MFIX);
      const float p2 = __expf(v2 - MFIX), p3 = __expf(v3 - MFIX);
      lsum[r] += (p0 + p1) + (p2 + p3);
      Pt[lrow * 68 + c] = f2b(p0);
      Pt[lrow * 68 + 16 + c] = f2b(p1);
      Pt[lrow * 68 + 32 + c] = f2b(p2);
      Pt[lrow * 68 + 48 + c] = f2b(p3);
    }

    // ---- O += P V ----
#pragma unroll
    for (int kc2 = 0; kc2 < 2; ++kc2) {
      bf16x8 pf = *(const bf16x8*)&Pt[(w * 16 + c) * 68 + kc2 * 32 + quad * 8];
#pragma unroll
      for (int n2 = 0; n2 < 8; ++n2) {
        bf16x8 vf = *(const bf16x8*)&Vt[(n2 * 16 + c) * 68 + kc2 * 32 + quad * 8];
        acc_o[n2] = __builtin_amdgcn_mfma_f32_16x16x32_bf16(pf, vf, acc_o[n2], 0, 0, 0);
      }
    }
    __syncthreads();
  }

  // one cross-lane l reduction (within 16-lane c-group)
#pragma unroll
  for (int r = 0; r < 4; ++r) {
    float l = lsum[r];
    l += __shfl_xor(l, 1, 64);
    l += __shfl_xor(l, 2, 64);
    l += __shfl_xor(l, 4, 64);
    l += __shfl_xor(l, 8, 64);
    lsum[r] = l;
  }

#pragma unroll
  for (int r = 0; r < 4; ++r) {
    const float invl = 1.0f / lsum[r];
    const int qrow = qt * 64 + w * 16 + quad * 4 + r;
    unsigned short* op = O + ((size_t)(b * NT + qrow) * NH + h) * NHD + c;
#pragma unroll
    for (int n2 = 0; n2 < 8; ++n2) op[n2 * 16] = f2b(acc_o[n2][r] * invl);
  }
}

extern "C" void kernel_launch(void* const* d_in, const int* in_sizes, int n_in,
                              void* d_out, int out_size, void* d_ws, size_t ws_size,
                              hipStream_t stream) {
  (void)in_sizes; (void)n_in; (void)out_size; (void)ws_size;
  const float* q_input  = (const float*)d_in[0];
  const float* kv_input = (const float*)d_in[1];
  // d_in[2] = mask (static causal tril) — applied analytically
  const float* cosp = (const float*)d_in[3];
  const float* sinp = (const float*)d_in[4];
  const float* Wq = (const float*)d_in[5];
  const float* Wk = (const float*)d_in[6];
  const float* Wv = (const float*)d_in[7];
  const float* q_scale = (const float*)d_in[8];
  const float* k_scale = (const float*)d_in[9];
  const float* Wo = (const float*)d_in[10];
  float* out = (float*)d_out;

  // workspace carve (~108 MB) with lifetime-safe aliases
  char* p = (char*)d_ws;
  float* Q32  = (float*)p; p += (size_t)NB * NT * ND * 4;        // 33.5 MB
  float* KVp  = (float*)p; p += (size_t)NB * NT * 1024 * 4;      // 16.8 MB (K cols 0..511, V cols 512..1023)
  unsigned short* Qb16  = (unsigned short*)p; p += (size_t)NB * NT * ND * 2;  // 16.8 MB
  unsigned short* KVb16 = (unsigned short*)p; p += (size_t)NB * NT * ND * 2;  // 16.8 MB
  unsigned short* Kh  = (unsigned short*)p; p += (size_t)NB * NKVH * NT * NHD * 2;  // 4.2 MB
  unsigned short* Vtg = (unsigned short*)p; p += (size_t)NB * NKVH * NT * NHD * 2;  // 4.2 MB
  unsigned short* Wqt  = (unsigned short*)p; p += (size_t)ND * ND * 2;         // 8.4 MB
  unsigned short* WkvT = (unsigned short*)p; p += (size_t)1024 * ND * 2;       // 4.2 MB
  unsigned short* Wot  = (unsigned short*)p; p += (size_t)ND * ND * 2;         // 8.4 MB
  // aliases: Qb16 dead after Q-proj -> reuse as Ob; KVb16 dead after KV-proj -> reuse as Qh
  unsigned short* Ob = Qb16;
  unsigned short* Qh = KVb16;

  const dim3 blk(256);
  const int M = NB * NT;  // 4096

  // activation f32 -> bf16 (one-time)
  f2bf<<<dim3(M * ND / 2048), blk, 0, stream>>>(q_input, Qb16);
  f2bf<<<dim3(M * ND / 2048), blk, 0, stream>>>(kv_input, KVb16);

  // weight transpose+convert; Wk|Wv fused into WkvT (rows 0..511 = K, 512..1023 = V)
  wtrans<<<dim3(ND / 32, ND / 32), blk, 0, stream>>>(Wq, Wqt, ND, ND);
  wtrans<<<dim3(512 / 32, ND / 32), blk, 0, stream>>>(Wk, WkvT, ND, 512);
  wtrans<<<dim3(512 / 32, ND / 32), blk, 0, stream>>>(Wv, WkvT + (size_t)512 * ND, ND, 512);
  wtrans<<<dim3(ND / 32, ND / 32), blk, 0, stream>>>(Wo, Wot, ND, ND);

  // Q-proj + KV-proj fused into one dispatch (512 + 256 blocks)
  gemm_qkv<<<dim3(768), blk, 0, stream>>>(Qb16, Wqt, Q32, KVb16, WkvT, KVp);

  // fixups: rmsnorm + rope + relayout; Q gets 1/sqrt(HD) folded in
  rmsnorm_rope<<<dim3(NB * NT * NH / 4), blk, 0, stream>>>(Q32, Qh, q_scale, cosp, sinp,
                                                           NH, ND, 0.08838834764831845f);
  rmsnorm_rope<<<dim3(NB * NT * NKVH / 4), blk, 0, stream>>>(KVp, Kh, k_scale, cosp, sinp,
                                                             NKVH, 1024, 1.0f);
  vtrans<<<dim3(NT / 32, NHD / 32, NB * NKVH), blk, 0, stream>>>(KVp + 512, Vtg, 1024);

  // MFMA causal GQA flash attention -> Ob (B,T,H,HD)
  attn64<<<dim3(NB * NH, 32), blk, 0, stream>>>(Qh, Kh, Vtg, Ob);

  // output projection -> d_out (f32)
  gemm128<<<dim3(ND / 128, M / 128), blk, 0, stream>>>(Ob, Wot, out, M, ND, ND);
}

// Round 5
// 354.753 us; speedup vs baseline: 1.2016x; 1.0329x over previous
//
#include <hip/hip_runtime.h>

// Problem constants (B,T,D,H,KVH fixed by the reference)
#define NB 2
#define NT 2048
#define ND 2048
#define NH 16
#define NKVH 4
#define NHD 128
#define NHALF 64
#define NREP (NH / NKVH)
#define MFIX 12.0f  // fixed softmax max: |score| <= sqrt(128) ~= 11.32 after zc-rmsnorm

typedef __bf16 bf16x8 __attribute__((ext_vector_type(8)));
typedef unsigned short u16x8 __attribute__((ext_vector_type(8)));
typedef float f32x4 __attribute__((ext_vector_type(4)));

__device__ __forceinline__ unsigned short f2b(float f) {
  union { float f; unsigned int u; } v; v.f = f;
  unsigned int r = v.u + 0x7FFFu + ((v.u >> 16) & 1u);
  return (unsigned short)(r >> 16);
}
__device__ __forceinline__ float b2f(unsigned short h) {
  union { unsigned int u; float f; } v; v.u = ((unsigned int)h) << 16;
  return v.f;
}

// async global->LDS DMA, 16B per lane. LDS dest = wave-uniform base + lane*16.
__device__ __forceinline__ void glds16(const unsigned short* g, unsigned short* l) {
  __builtin_amdgcn_global_load_lds(
      (__attribute__((address_space(1))) unsigned int*)(unsigned long long)g,
      (__attribute__((address_space(3))) unsigned int*)(unsigned int)(unsigned long long)l,
      16, 0, 0);
}

// ---------- fused prep: f2bf(q) | f2bf(kv) | wtrans x4, one dispatch ----------
// All segments independent; branch is block-uniform so the wtrans barrier is safe.
// Launch-gap removal: was 6 dispatches (~10us gap each), now 1.
__device__ __forceinline__ void f2bf_body(const float* __restrict__ in,
                                          unsigned short* __restrict__ out, int lb) {
  const size_t i = (size_t)(lb * 256 + threadIdx.x) * 8;
  float4 a = *(const float4*)(in + i);
  float4 b = *(const float4*)(in + i + 4);
  u16x8 r;
  r[0] = f2b(a.x); r[1] = f2b(a.y); r[2] = f2b(a.z); r[3] = f2b(a.w);
  r[4] = f2b(b.x); r[5] = f2b(b.y); r[6] = f2b(b.z); r[7] = f2b(b.w);
  *(u16x8*)(out + i) = r;
}

__device__ __forceinline__ void wtrans_body(const float* __restrict__ in,
                                            unsigned short* __restrict__ out,
                                            int K, int N, int bx, int by,
                                            float (*tile)[33]) {
  const int k0 = by * 32, n0 = bx * 32;
  const int x = threadIdx.x & 31, y8 = threadIdx.x >> 5;
#pragma unroll
  for (int j = 0; j < 4; ++j) {
    const int y = y8 + j * 8;
    tile[y][x] = in[(size_t)(k0 + y) * N + n0 + x];
  }
  __syncthreads();
#pragma unroll
  for (int j = 0; j < 4; ++j) {
    const int y = y8 + j * 8;
    out[(size_t)(n0 + y) * K + k0 + x] = f2b(tile[x][y]);
  }
}

__global__ __launch_bounds__(256) void prep_all(const float* __restrict__ q_input,
                                                unsigned short* __restrict__ Qb16,
                                                const float* __restrict__ kv_input,
                                                unsigned short* __restrict__ KVb16,
                                                const float* __restrict__ Wq,
                                                unsigned short* __restrict__ Wqt,
                                                const float* __restrict__ Wk,
                                                const float* __restrict__ Wv,
                                                unsigned short* __restrict__ WkvT,
                                                const float* __restrict__ Wo,
                                                unsigned short* __restrict__ Wot) {
  __shared__ float tile[32][33];
  const int l = blockIdx.x;
  if (l < 4096) {
    f2bf_body(q_input, Qb16, l);
  } else if (l < 8192) {
    f2bf_body(kv_input, KVb16, l - 4096);
  } else if (l < 12288) {
    const int l2 = l - 8192;
    wtrans_body(Wq, Wqt, 2048, 2048, l2 & 63, l2 >> 6, tile);
  } else if (l < 13312) {
    const int l2 = l - 12288;
    wtrans_body(Wk, WkvT, 2048, 512, l2 & 15, l2 >> 4, tile);
  } else if (l < 14336) {
    const int l2 = l - 13312;
    wtrans_body(Wv, WkvT + (size_t)512 * 2048, 2048, 512, l2 & 15, l2 >> 4, tile);
  } else {
    const int l2 = l - 14336;
    wtrans_body(Wo, Wot, 2048, 2048, l2 & 63, l2 >> 6, tile);
  }
}

// ---------- GEMM core: C(:,N) tile (m0,n0) = A(M,K)bf16 @ Bt(N,K)bf16^T ----------
// 128x128 tile, BK=64, 2-phase double-buffered global_load_lds pipeline.
// LDS layout LINEAR [128][64]; conflict-free via XOR-granule swizzle on BOTH
// sides (rule #21): staging fetches global granule ((lane&7)^(lane>>3)) of its
// row; reads XOR the granule with (row&7). One __syncthreads per K-step.
__device__ __forceinline__ void gemm_core(const unsigned short* __restrict__ A,
                                          const unsigned short* __restrict__ Bt,
                                          float* __restrict__ C,
                                          int N, int K, int m0, int n0,
                                          unsigned short* As, unsigned short* Bs) {
  const int tid = threadIdx.x;
  const int wave = tid >> 6, lane = tid & 63;
  const int wm = wave >> 1, wn = wave & 1;
  const int quad = lane >> 4, c = lane & 15;
  const int lr = lane >> 3;                 // 0..7: row within an 8-row stage group
  const int gsw = ((lane & 7) ^ lr) * 8;    // pre-swizzled source granule (shorts)

  const unsigned short* pa[4];
  const unsigned short* pb[4];
  unsigned short* da[4];
  unsigned short* db[4];
#pragma unroll
  for (int j = 0; j < 4; ++j) {
    const int rb = j * 32 + wave * 8;       // 8-row group base (multiple of 8)
    pa[j] = A + (size_t)(m0 + rb + lr) * K + gsw;
    pb[j] = Bt + (size_t)(n0 + rb + lr) * K + gsw;
    da[j] = As + rb * 64;
    db[j] = Bs + rb * 64;
  }

  f32x4 acc[4][4] = {};
  const int nsteps = K >> 6;
  int cur = 0;

  // prologue: stage K-step 0 into buffer 0
#pragma unroll
  for (int j = 0; j < 4; ++j) { glds16(pa[j], da[j]); glds16(pb[j], db[j]); }
  __syncthreads();

  for (int t = 0; t < nsteps; ++t) {
    const int nxt = (cur ^ 1) * (128 * 64);
    if (t + 1 < nsteps) {  // issue next K-step's DMA; latency hides under MFMA
      const int kn = (t + 1) << 6;
#pragma unroll
      for (int j = 0; j < 4; ++j) {
        glds16(pa[j] + kn, da[j] + nxt);
        glds16(pb[j] + kn, db[j] + nxt);
      }
    }
    const unsigned short* Ab = As + cur * (128 * 64);
    const unsigned short* Bb = Bs + cur * (128 * 64);
#pragma unroll
    for (int kk = 0; kk < 2; ++kk) {
      const int g = ((kk * 4 + quad) ^ (c & 7)) * 8;  // swizzled read granule
      bf16x8 af[4];
#pragma unroll
      for (int sm = 0; sm < 4; ++sm)
        af[sm] = *(const bf16x8*)&Ab[(wm * 64 + sm * 16 + c) * 64 + g];
#pragma unroll
      for (int sn = 0; sn < 4; ++sn) {
        bf16x8 bfr = *(const bf16x8*)&Bb[(wn * 64 + sn * 16 + c) * 64 + g];
#pragma unroll
        for (int sm = 0; sm < 4; ++sm)
          acc[sm][sn] = __builtin_amdgcn_mfma_f32_16x16x32_bf16(af[sm], bfr, acc[sm][sn], 0, 0, 0);
      }
    }
    // drain own glds (vmcnt) + join: next buffer globally ready; all reads of
    // buf[cur] happened above, so flipping is safe.
    __syncthreads();
    cur ^= 1;
  }

#pragma unroll
  for (int sm = 0; sm < 4; ++sm)
#pragma unroll
    for (int sn = 0; sn < 4; ++sn) {
      const int row = m0 + wm * 64 + sm * 16 + quad * 4;
      const int col = n0 + wn * 64 + sn * 16 + c;
#pragma unroll
      for (int r = 0; r < 4; ++r)
        C[(size_t)(row + r) * N + col] = acc[sm][sn][r];
    }
}

// ---------- standalone GEMM (O-projection) ----------
__global__ __launch_bounds__(256) void gemm128(const unsigned short* __restrict__ A,
                                               const unsigned short* __restrict__ Bt,
                                               float* __restrict__ C,
                                               int M, int N, int K) {
  __shared__ unsigned short As[2 * 128 * 64];
  __shared__ unsigned short Bs[2 * 128 * 64];
  // T1 XCD swizzle (bijective: nwg % 8 == 0 for all our grids)
  const int gx = gridDim.x;
  const int nwg = gx * gridDim.y;
  int lin = blockIdx.y * gx + blockIdx.x;
  lin = (lin & 7) * (nwg >> 3) + (lin >> 3);
  gemm_core(A, Bt, C, N, K, (lin / gx) * 128, (lin % gx) * 128, As, Bs);
}

// ---------- fused Q-proj + KV-proj in one dispatch (768 blocks) ----------
__global__ __launch_bounds__(256) void gemm_qkv(const unsigned short* __restrict__ Aq,
                                                const unsigned short* __restrict__ Wq,
                                                float* __restrict__ Cq,
                                                const unsigned short* __restrict__ Akv,
                                                const unsigned short* __restrict__ Wkv,
                                                float* __restrict__ Ckv) {
  __shared__ unsigned short As[2 * 128 * 64];
  __shared__ unsigned short Bs[2 * 128 * 64];
  int lin = blockIdx.x;
  lin = (lin & 7) * 96 + (lin >> 3);  // nwg = 768
  if (lin < 512) {
    gemm_core(Aq, Wq, Cq, 2048, 2048, (lin >> 4) * 128, (lin & 15) * 128, As, Bs);
  } else {
    const int l2 = lin - 512;
    gemm_core(Akv, Wkv, Ckv, 1024, 2048, (l2 >> 3) * 128, (l2 & 7) * 128, As, Bs);
  }
}

// ---------- fused fixups: rmsnorm+rope(Q) | rmsnorm+rope(K) | vtrans ----------
// All depend only on gemm_qkv; was 3 dispatches, now 1.
__device__ __forceinline__ void rmsnorm_rope_body(const float* __restrict__ in,
                                                  unsigned short* __restrict__ out,
                                                  const float* __restrict__ scale,
                                                  const float* __restrict__ cosp,
                                                  const float* __restrict__ sinp,
                                                  int nh, int instride, float outscale,
                                                  int lb) {
  const int wid = lb * 4 + (threadIdx.x >> 6);
  const int lane = threadIdx.x & 63;
  const int h = wid % nh;
  const int t = (wid / nh) % NT;
  const int b = wid / (nh * NT);
  const float* x = in + (size_t)(b * NT + t) * instride + h * NHD;
  float x1 = x[lane], x2 = x[lane + NHALF];
  float ss = x1 * x1 + x2 * x2;
#pragma unroll
  for (int m = 1; m < 64; m <<= 1) ss += __shfl_xor(ss, m, 64);
  const float inv = 1.0f / sqrtf(ss * (1.0f / NHD) + 1e-6f);
  const float n1 = (1.0f + scale[lane]) * x1 * inv;
  const float n2 = (1.0f + scale[lane + NHALF]) * x2 * inv;
  const float cc = cosp[t * NHALF + lane], s = sinp[t * NHALF + lane];
  const size_t ob = (((size_t)b * nh + h) * NT + t) * NHD;
  out[ob + lane] = f2b((n1 * cc - n2 * s) * outscale);
  out[ob + lane + NHALF] = f2b((n2 * cc + n1 * s) * outscale);
}

__global__ __launch_bounds__(256) void fixup_all(const float* __restrict__ Q32,
                                                 unsigned short* __restrict__ Qh,
                                                 const float* __restrict__ KVp,
                                                 unsigned short* __restrict__ Kh,
                                                 unsigned short* __restrict__ Vtg,
                                                 const float* __restrict__ q_scale,
                                                 const float* __restrict__ k_scale,
                                                 const float* __restrict__ cosp,
                                                 const float* __restrict__ sinp) {
  __shared__ float tile[32][33];
  const int l = blockIdx.x;
  if (l < 16384) {
    rmsnorm_rope_body(Q32, Qh, q_scale, cosp, sinp, NH, ND, 0.08838834764831845f, l);
  } else if (l < 20480) {
    rmsnorm_rope_body(KVp, Kh, k_scale, cosp, sinp, NKVH, 1024, 1.0f, l - 16384);
  } else {
    // vtrans: V cols of KVp (offset 512) -> (B,KVH,HD,T) bf16
    const int l2 = l - 20480;
    const int bx = l2 & 63, by = (l2 >> 6) & 3, bg = l2 >> 8;
    const int b = bg >> 2, g = bg & 3;
    const int t0 = bx * 32, d0 = by * 32;
    const int x = threadIdx.x & 31, y8 = threadIdx.x >> 5;
    const float* vin = KVp + 512;
#pragma unroll
    for (int j = 0; j < 4; ++j) {
      const int y = y8 + j * 8;  // t offset
      tile[y][x] = vin[(size_t)(b * NT + t0 + y) * 1024 + g * NHD + d0 + x];
    }
    __syncthreads();
#pragma unroll
    for (int j = 0; j < 4; ++j) {
      const int y = y8 + j * 8;  // d offset
      Vtg[((size_t)bg * NHD + d0 + y) * NT + t0 + x] = f2b(tile[x][y]);
    }
  }
}

// ---------- MFMA causal flash attention, 64-row Q-tiles ----------
// grid (B*H, 32). Block = 64 q-rows (4 waves x 16 rows), K-tiles of 64 keys.
// Fixed-max softmax (MFIX): no per-tile reductions, no O-rescale; one l-reduction at end.
// T14 prefetch: next K/V tile loaded to regs during compute.
// LDS strides 132/68 shorts; LDS 43008 B -> 3 blocks/CU.
__global__ __launch_bounds__(256, 3) void attn64(const unsigned short* __restrict__ Qh,
                                                 const unsigned short* __restrict__ Kh,
                                                 const unsigned short* __restrict__ Vtg,
                                                 unsigned short* __restrict__ O) {
  __shared__ unsigned short Kt[64 * 132];  // [key][d]
  __shared__ unsigned short Vt[128 * 68];  // [d][key]
  __shared__ unsigned short Pt[64 * 68];   // [qrow][key], wave-private 16-row slabs
  const int bh = blockIdx.x;
  const int b = bh / NH, h = bh % NH, g = h / NREP;
  const int y = blockIdx.y;
  const int a = y & 7, bb = y >> 3;
  // CU-balanced qt map: each a-group gets {a, a+8, 31-a, 23-a} (sum = 62, constant)
  const int qt = (bb == 0) ? a : (bb == 1) ? a + 8 : (bb == 2) ? 31 - a : 23 - a;
  const int tid = threadIdx.x;
  const int w = tid >> 6, lane = tid & 63;
  const int quad = lane >> 4, c = lane & 15;

  // Q A-fragments: rows qt*64 + w*16 + c, k = ch*32 + quad*8 + j
  bf16x8 qf[4];
  {
    const unsigned short* qp =
        Qh + ((size_t)(b * NH + h) * NT + qt * 64 + w * 16 + c) * NHD + quad * 8;
#pragma unroll
    for (int ch = 0; ch < 4; ++ch) qf[ch] = *(const bf16x8*)(qp + ch * 32);
  }

  f32x4 acc_o[8] = {};              // [n2]: row quad*4+r, dim n2*16+c
  float lsum[4] = {0.f, 0.f, 0.f, 0.f};
  const size_t kbase = (size_t)(b * NKVH + g) * NT * NHD;
  const size_t vbase = (size_t)(b * NKVH + g) * NHD * NT;
  const int nkt = qt + 1;

  // prologue: K/V tile 0 -> regs
  u16x8 kreg[4], vreg[4];
#pragma unroll
  for (int j = 0; j < 4; ++j) {
    const int f = j * 256 + tid;
    kreg[j] = *(const u16x8*)&Kh[kbase + (size_t)(f >> 4) * NHD + (f & 15) * 8];
    vreg[j] = *(const u16x8*)&Vtg[vbase + (size_t)(f >> 3) * NT + (f & 7) * 8];
  }

  for (int kt = 0; kt < nkt; ++kt) {
    // write staged tile to LDS
#pragma unroll
    for (int j = 0; j < 4; ++j) {
      const int f = j * 256 + tid;
      *(u16x8*)&Kt[(f >> 4) * 132 + (f & 15) * 8] = kreg[j];
      *(u16x8*)&Vt[(f >> 3) * 68 + (f & 7) * 8] = vreg[j];
    }
    __syncthreads();

    // prefetch next tile into regs (vmcnt drains at end-of-iter barrier,
    // hidden under QK+softmax+PV)
    if (kt + 1 < nkt) {
      const int k0 = (kt + 1) * 64;
#pragma unroll
      for (int j = 0; j < 4; ++j) {
        const int f = j * 256 + tid;
        kreg[j] = *(const u16x8*)&Kh[kbase + (size_t)(k0 + (f >> 4)) * NHD + (f & 15) * 8];
        vreg[j] = *(const u16x8*)&Vtg[vbase + (size_t)(f >> 3) * NT + k0 + (f & 7) * 8];
      }
    }

    // ---- S = Q K^T (16 x 64) ----
    f32x4 s[4] = {};
#pragma unroll
    for (int n = 0; n < 4; ++n)
#pragma unroll
      for (int ch = 0; ch < 4; ++ch) {
        bf16x8 kf = *(const bf16x8*)&Kt[(n * 16 + c) * 132 + ch * 32 + quad * 8];
        s[n] = __builtin_amdgcn_mfma_f32_16x16x32_bf16(qf[ch], kf, s[n], 0, 0, 0);
      }

    // ---- fixed-max softmax; P -> LDS (bf16) ----
    const bool dmask = (kt == qt);  // only the diagonal tile masks
#pragma unroll
    for (int r = 0; r < 4; ++r) {
      float v0 = s[0][r], v1 = s[1][r], v2 = s[2][r], v3 = s[3][r];
      const int lrow = w * 16 + quad * 4 + r;  // row within block; key offset n*16+c
      if (dmask) {
        if (c > lrow) v0 = -1e30f;
        if (16 + c > lrow) v1 = -1e30f;
        if (32 + c > lrow) v2 = -1e30f;
        if (48 + c > lrow) v3 = -1e30f;
      }
      const float p0 = __expf(v0 - MFIX), p1 = __expf(v1 - MFIX);
      const float p2 = __expf(v2 - MFIX), p3 = __expf(v3 - MFIX);
      lsum[r] += (p0 + p1) + (p2 + p3);
      Pt[lrow * 68 + c] = f2b(p0);
      Pt[lrow * 68 + 16 + c] = f2b(p1);
      Pt[lrow * 68 + 32 + c] = f2b(p2);
      Pt[lrow * 68 + 48 + c] = f2b(p3);
    }

    // ---- O += P V ----
#pragma unroll
    for (int kc2 = 0; kc2 < 2; ++kc2) {
      bf16x8 pf = *(const bf16x8*)&Pt[(w * 16 + c) * 68 + kc2 * 32 + quad * 8];
#pragma unroll
      for (int n2 = 0; n2 < 8; ++n2) {
        bf16x8 vf = *(const bf16x8*)&Vt[(n2 * 16 + c) * 68 + kc2 * 32 + quad * 8];
        acc_o[n2] = __builtin_amdgcn_mfma_f32_16x16x32_bf16(pf, vf, acc_o[n2], 0, 0, 0);
      }
    }
    __syncthreads();
  }

  // one cross-lane l reduction (within 16-lane c-group)
#pragma unroll
  for (int r = 0; r < 4; ++r) {
    float l = lsum[r];
    l += __shfl_xor(l, 1, 64);
    l += __shfl_xor(l, 2, 64);
    l += __shfl_xor(l, 4, 64);
    l += __shfl_xor(l, 8, 64);
    lsum[r] = l;
  }

#pragma unroll
  for (int r = 0; r < 4; ++r) {
    const float invl = 1.0f / lsum[r];
    const int qrow = qt * 64 + w * 16 + quad * 4 + r;
    unsigned short* op = O + ((size_t)(b * NT + qrow) * NH + h) * NHD + c;
#pragma unroll
    for (int n2 = 0; n2 < 8; ++n2) op[n2 * 16] = f2b(acc_o[n2][r] * invl);
  }
}

extern "C" void kernel_launch(void* const* d_in, const int* in_sizes, int n_in,
                              void* d_out, int out_size, void* d_ws, size_t ws_size,
                              hipStream_t stream) {
  (void)in_sizes; (void)n_in; (void)out_size; (void)ws_size;
  const float* q_input  = (const float*)d_in[0];
  const float* kv_input = (const float*)d_in[1];
  // d_in[2] = mask (static causal tril) — applied analytically
  const float* cosp = (const float*)d_in[3];
  const float* sinp = (const float*)d_in[4];
  const float* Wq = (const float*)d_in[5];
  const float* Wk = (const float*)d_in[6];
  const float* Wv = (const float*)d_in[7];
  const float* q_scale = (const float*)d_in[8];
  const float* k_scale = (const float*)d_in[9];
  const float* Wo = (const float*)d_in[10];
  float* out = (float*)d_out;

  // workspace carve (~108 MB) with lifetime-safe aliases
  char* p = (char*)d_ws;
  float* Q32  = (float*)p; p += (size_t)NB * NT * ND * 4;        // 33.5 MB
  float* KVp  = (float*)p; p += (size_t)NB * NT * 1024 * 4;      // 16.8 MB (K cols 0..511, V cols 512..1023)
  unsigned short* Qb16  = (unsigned short*)p; p += (size_t)NB * NT * ND * 2;  // 16.8 MB
  unsigned short* KVb16 = (unsigned short*)p; p += (size_t)NB * NT * ND * 2;  // 16.8 MB
  unsigned short* Kh  = (unsigned short*)p; p += (size_t)NB * NKVH * NT * NHD * 2;  // 4.2 MB
  unsigned short* Vtg = (unsigned short*)p; p += (size_t)NB * NKVH * NT * NHD * 2;  // 4.2 MB
  unsigned short* Wqt  = (unsigned short*)p; p += (size_t)ND * ND * 2;         // 8.4 MB
  unsigned short* WkvT = (unsigned short*)p; p += (size_t)1024 * ND * 2;       // 4.2 MB
  unsigned short* Wot  = (unsigned short*)p; p += (size_t)ND * ND * 2;         // 8.4 MB
  // aliases: Qb16 dead after Q-proj -> reuse as Ob; KVb16 dead after KV-proj -> reuse as Qh
  unsigned short* Ob = Qb16;
  unsigned short* Qh = KVb16;

  const dim3 blk(256);
  const int M = NB * NT;  // 4096

  // 1) all prep (activation cvt + weight transposes) in one dispatch
  prep_all<<<dim3(18432), blk, 0, stream>>>(q_input, Qb16, kv_input, KVb16,
                                            Wq, Wqt, Wk, Wv, WkvT, Wo, Wot);

  // 2) Q-proj + KV-proj fused (512 + 256 blocks)
  gemm_qkv<<<dim3(768), blk, 0, stream>>>(Qb16, Wqt, Q32, KVb16, WkvT, KVp);

  // 3) all fixups (rmsnorm+rope Q, rmsnorm+rope K, vtrans) in one dispatch
  fixup_all<<<dim3(22528), blk, 0, stream>>>(Q32, Qh, KVp, Kh, Vtg,
                                             q_scale, k_scale, cosp, sinp);

  // 4) MFMA causal GQA flash attention -> Ob (B,T,H,HD)
  attn64<<<dim3(NB * NH, 32), blk, 0, stream>>>(Qh, Kh, Vtg, Ob);

  // 5) output projection -> d_out (f32)
  gemm128<<<dim3(ND / 128, M / 128), blk, 0, stream>>>(Ob, Wot, out, M, ND, ND);
}